// Round 1
// baseline (3357.190 us; speedup 1.0000x reference)
//
#include <hip/hip_runtime.h>
#include <math.h>

// Problem constants (from reference)
#define N0_C  100000
#define N1_C  40000
#define N2_C  10000
#define E1_C  640000
#define E2_C  160000
#define D_IN_C  256
#define D_HID_C 256
#define D_OUT_C 128

// ---------------------------------------------------------------------------
// zero fill (ws is re-poisoned to 0xAA before every launch)
// ---------------------------------------------------------------------------
__global__ void zero_kernel(float* __restrict__ p, int n4) {
    int i = blockIdx.x * blockDim.x + threadIdx.x;
    int stride = gridDim.x * blockDim.x;
    float4 z = make_float4(0.f, 0.f, 0.f, 0.f);
    for (; i < n4; i += stride) ((float4*)p)[i] = z;
}

// ---------------------------------------------------------------------------
// scatter-add: one wave (64 lanes) per edge, float4 per lane (256 channels)
// ---------------------------------------------------------------------------
__global__ void scatter_add_kernel(const float* __restrict__ feat,
                                   const int* __restrict__ src,
                                   const int* __restrict__ dst,
                                   float* __restrict__ aggr,
                                   float* __restrict__ cnt,
                                   int E) {
    long long tid = (long long)blockIdx.x * blockDim.x + threadIdx.x;
    int e    = (int)(tid >> 6);
    int lane = (int)(tid & 63);
    if (e >= E) return;
    int s = src[e];
    int d = dst[e];
    const float4 v = *(const float4*)(feat + (size_t)s * 256 + lane * 4);
    float* a = aggr + (size_t)d * 256 + lane * 4;
    atomicAdd(a + 0, v.x);
    atomicAdd(a + 1, v.y);
    atomicAdd(a + 2, v.z);
    atomicAdd(a + 3, v.w);
    if (lane == 0) atomicAdd(cnt + d, 1.0f);
}

// ---------------------------------------------------------------------------
// fused GEMM: out = act( (aggr/max(cnt,1)) @ Wa + x2 @ Wx + bias )
//   A matrices are (M,256) row-major, W are (256,N) row-major.
//   64x64 tile per block, 256 threads, 4x4 micro-tile per thread.
//   act: 0 = relu, 1 = sigmoid
// ---------------------------------------------------------------------------
__global__ __launch_bounds__(256)
void gemm_fused_kernel(const float* __restrict__ aggr,
                       const float* __restrict__ cnt,
                       const float* __restrict__ x2,
                       const float* __restrict__ Wa,
                       const float* __restrict__ Wx,
                       const float* __restrict__ bias,
                       float* __restrict__ out,
                       int M, int N, int act) {
    // As[k][row]: stride 68 floats -> 68*4=272 B row pitch, 16B-aligned for
    // ds_read_b128 at As[k][4*tx]; bank = (4k + 4tx) % 32 -> <=2-way (free).
    __shared__ float As[64][68];

    const int tx = threadIdx.x & 15;   // row group (4 rows)
    const int ty = threadIdx.x >> 4;   // col group (4 cols)
    const int row0 = blockIdx.y * 64;
    const int col0 = blockIdx.x * 64;

    float acc[4][4] = {{0.f}};

    for (int p = 0; p < 2; ++p) {
        const float* __restrict__ A = p ? x2 : aggr;
        const float* __restrict__ W = p ? Wx : Wa;
        for (int kt = 0; kt < 4; ++kt) {
            // ---- stage A-tile (64 rows x 64 k), transposed into LDS ----
            #pragma unroll
            for (int it = 0; it < 4; ++it) {
                int idx = threadIdx.x + it * 256;
                int r  = idx >> 4;     // 0..63
                int kg = idx & 15;     // 0..15 (4 k's each)
                int row = row0 + r;
                if (row > M - 1) row = M - 1;   // tail clamp (stores guarded)
                float4 v = *(const float4*)(A + (size_t)row * 256 + kt * 64 + kg * 4);
                if (p == 0) {
                    float inv = 1.0f / fmaxf(cnt[row], 1.0f);
                    v.x *= inv; v.y *= inv; v.z *= inv; v.w *= inv;
                }
                As[kg * 4 + 0][r] = v.x;
                As[kg * 4 + 1][r] = v.y;
                As[kg * 4 + 2][r] = v.z;
                As[kg * 4 + 3][r] = v.w;
            }
            __syncthreads();

            // ---- inner product over this k-tile ----
            #pragma unroll 8
            for (int k = 0; k < 64; ++k) {
                float4 a4 = *(const float4*)&As[k][tx * 4];
                float4 w4 = *(const float4*)(W + (size_t)(kt * 64 + k) * N + col0 + ty * 4);
                float av[4] = {a4.x, a4.y, a4.z, a4.w};
                float wv[4] = {w4.x, w4.y, w4.z, w4.w};
                #pragma unroll
                for (int i = 0; i < 4; ++i)
                    #pragma unroll
                    for (int j = 0; j < 4; ++j)
                        acc[i][j] += av[i] * wv[j];
            }
            __syncthreads();
        }
    }

    // ---- epilogue: bias + activation + store ----
    float4 b4 = *(const float4*)(bias + col0 + ty * 4);
    float bv[4] = {b4.x, b4.y, b4.z, b4.w};
    #pragma unroll
    for (int i = 0; i < 4; ++i) {
        int r = row0 + tx * 4 + i;
        if (r < M) {
            float o[4];
            #pragma unroll
            for (int j = 0; j < 4; ++j) {
                float v = acc[i][j] + bv[j];
                if (act == 0) v = fmaxf(v, 0.f);
                else          v = 1.0f / (1.0f + __expf(-v));
                o[j] = v;
            }
            *(float4*)(out + (size_t)r * N + col0 + ty * 4) = *(float4*)o;
        }
    }
}

// ---------------------------------------------------------------------------
// launch
// ---------------------------------------------------------------------------
extern "C" void kernel_launch(void* const* d_in, const int* in_sizes, int n_in,
                              void* d_out, int out_size, void* d_ws, size_t ws_size,
                              hipStream_t stream) {
    const float* x   = (const float*)d_in[0];
    const float* W1l = (const float*)d_in[1];
    const float* b1  = (const float*)d_in[2];
    const float* W1r = (const float*)d_in[3];
    const float* W2l = (const float*)d_in[4];
    const float* b2  = (const float*)d_in[5];
    const float* W2r = (const float*)d_in[6];
    const int* src1  = (const int*)d_in[7];
    const int* dst1  = (const int*)d_in[8];
    const int* src2  = (const int*)d_in[9];
    const int* dst2  = (const int*)d_in[10];
    float* out = (float*)d_out;

    // workspace layout (floats)
    float* ws = (float*)d_ws;
    float* aggr1 = ws;                                   // N1*256 = 10,240,000
    float* h     = aggr1 + (size_t)N1_C * 256;           // N1*256 = 10,240,000
    float* aggr2 = h + (size_t)N1_C * 256;               // N2*256 =  2,560,000
    float* cnt1  = aggr2 + (size_t)N2_C * 256;           // N1     =     40,000
    float* cnt2  = cnt1 + N1_C;                          // N2     =     10,000

    // zero aggr1 (10.24M floats) and aggr2+cnt1+cnt2 (2.61M floats, contiguous)
    {
        int n4a = (N1_C * 256) / 4;
        int n4b = (N2_C * 256 + N1_C + N2_C) / 4;  // 2,610,000 / 4
        zero_kernel<<<2048, 256, 0, stream>>>(aggr1, n4a);
        zero_kernel<<<1024, 256, 0, stream>>>(aggr2, n4b);
    }

    // layer 1 scatter: aggr1 += x[src1] grouped by dst1
    {
        long long threads = (long long)E1_C * 64;
        int blocks = (int)((threads + 255) / 256);
        scatter_add_kernel<<<blocks, 256, 0, stream>>>(x, src1, dst1, aggr1, cnt1, E1_C);
    }

    // layer 1 GEMM: h = relu(aggr1/cnt @ W1l + b1 + x[:N1] @ W1r)
    {
        dim3 grid(D_HID_C / 64, N1_C / 64);  // (4, 625)
        gemm_fused_kernel<<<grid, 256, 0, stream>>>(aggr1, cnt1, x, W1l, W1r, b1, h,
                                                    N1_C, D_HID_C, 0);
    }

    // layer 2 scatter: aggr2 += h[src2] grouped by dst2
    {
        long long threads = (long long)E2_C * 64;
        int blocks = (int)((threads + 255) / 256);
        scatter_add_kernel<<<blocks, 256, 0, stream>>>(h, src2, dst2, aggr2, cnt2, E2_C);
    }

    // layer 2 GEMM: out = sigmoid(aggr2/cnt @ W2l + b2 + h[:N2] @ W2r)
    {
        dim3 grid(D_OUT_C / 64, (N2_C + 63) / 64);  // (2, 157)
        gemm_fused_kernel<<<grid, 256, 0, stream>>>(aggr2, cnt2, h, W2l, W2r, b2, out,
                                                    N2_C, D_OUT_C, 1);
    }
}

// Round 6
// 993.297 us; speedup vs baseline: 3.3798x; 3.3798x over previous
//
#include <hip/hip_runtime.h>
#include <math.h>

// Problem constants (from reference)
#define N0_C  100000
#define N1_C  40000
#define N2_C  10000
#define E1_C  640000
#define E2_C  160000
#define D_IN_C  256
#define D_HID_C 256
#define D_OUT_C 128

// All device-derived indices (dst values, atomic cursors, perm entries) are
// clamped before use: if any input were out of spec the result would be wrong
// but the kernel cannot fault. Cost: a few scalar min/max per edge.

// ---------------------------------------------------------------------------
// zero fill for int arrays (ws is re-poisoned to 0xAA before every launch)
// ---------------------------------------------------------------------------
__global__ void zero_int_kernel(int* __restrict__ p, int n) {
    int i = blockIdx.x * blockDim.x + threadIdx.x;
    int stride = gridDim.x * blockDim.x;
    for (; i < n; i += stride) p[i] = 0;
}

// ---------------------------------------------------------------------------
// CSR build step 1: histogram of dst (clamped)
// ---------------------------------------------------------------------------
__global__ void hist_kernel(const int* __restrict__ dst, int* __restrict__ deg,
                            int E, int n) {
    int e = blockIdx.x * blockDim.x + threadIdx.x;
    if (e >= E) return;
    int d = min(max(dst[e], 0), n - 1);
    atomicAdd(&deg[d], 1);
}

// ---------------------------------------------------------------------------
// CSR build step 2: exclusive prefix sum (single block, 256 threads).
// Writes rowstart[i] and cursor[i] (= rowstart[i], bumped by permute).
// ---------------------------------------------------------------------------
__global__ __launch_bounds__(256)
void scan_kernel(const int* __restrict__ deg, int* __restrict__ rowstart,
                 int* __restrict__ cursor, int n) {
    __shared__ int sums[256];
    const int chunk = (n + 255) / 256;
    const int b = threadIdx.x * chunk;
    const int e = min(b + chunk, n);
    int s = 0;
    for (int i = b; i < e; ++i) s += deg[i];
    sums[threadIdx.x] = s;
    __syncthreads();
    for (int off = 1; off < 256; off <<= 1) {
        int t = (threadIdx.x >= off) ? sums[threadIdx.x - off] : 0;
        __syncthreads();
        sums[threadIdx.x] += t;
        __syncthreads();
    }
    int run = (threadIdx.x == 0) ? 0 : sums[threadIdx.x - 1];
    for (int i = b; i < e; ++i) {
        rowstart[i] = run;
        cursor[i]   = run;
        run += deg[i];
    }
}

// ---------------------------------------------------------------------------
// CSR build step 3: permute src into dst-sorted order (pos clamped).
// After this, cursor[d] == rowstart[d] + deg[d] == row end.
// ---------------------------------------------------------------------------
__global__ void permute_kernel(const int* __restrict__ src, const int* __restrict__ dst,
                               int* __restrict__ cursor, int* __restrict__ perm,
                               int E, int n) {
    int e = blockIdx.x * blockDim.x + threadIdx.x;
    if (e >= E) return;
    int d = min(max(dst[e], 0), n - 1);
    int pos = atomicAdd(&cursor[d], 1);
    pos = min(max(pos, 0), E - 1);
    perm[pos] = src[e];
}

// ---------------------------------------------------------------------------
// gather-mean: one wave (64 lanes) per dst node; lane handles 4 channels.
// end = cursor[node] (post-permute row end). Writes aggr = mean (0 if empty).
// ---------------------------------------------------------------------------
__global__ __launch_bounds__(256)
void gather_mean_kernel(const float* __restrict__ feat,
                        const int* __restrict__ rowstart,
                        const int* __restrict__ cursor,
                        const int* __restrict__ perm,
                        float* __restrict__ aggr, int n, int E, int nfeat) {
    int node = blockIdx.x * 4 + (threadIdx.x >> 6);
    int lane = threadIdx.x & 63;
    if (node >= n) return;
    int beg = min(max(rowstart[node], 0), E);
    int end = min(max(cursor[node], beg), E);
    float4 acc = make_float4(0.f, 0.f, 0.f, 0.f);
    int i = beg;
    // 4-deep unroll for load ILP
    for (; i + 4 <= end; i += 4) {
        int s0 = min(max(perm[i + 0], 0), nfeat - 1);
        int s1 = min(max(perm[i + 1], 0), nfeat - 1);
        int s2 = min(max(perm[i + 2], 0), nfeat - 1);
        int s3 = min(max(perm[i + 3], 0), nfeat - 1);
        float4 v0 = *(const float4*)(feat + (size_t)s0 * 256 + lane * 4);
        float4 v1 = *(const float4*)(feat + (size_t)s1 * 256 + lane * 4);
        float4 v2 = *(const float4*)(feat + (size_t)s2 * 256 + lane * 4);
        float4 v3 = *(const float4*)(feat + (size_t)s3 * 256 + lane * 4);
        acc.x += v0.x + v1.x + v2.x + v3.x;
        acc.y += v0.y + v1.y + v2.y + v3.y;
        acc.z += v0.z + v1.z + v2.z + v3.z;
        acc.w += v0.w + v1.w + v2.w + v3.w;
    }
    for (; i < end; ++i) {
        int s = min(max(perm[i], 0), nfeat - 1);
        float4 v = *(const float4*)(feat + (size_t)s * 256 + lane * 4);
        acc.x += v.x; acc.y += v.y; acc.z += v.z; acc.w += v.w;
    }
    float inv = (end > beg) ? 1.0f / (float)(end - beg) : 0.0f;
    acc.x *= inv; acc.y *= inv; acc.z *= inv; acc.w *= inv;
    *(float4*)(aggr + (size_t)node * 256 + lane * 4) = acc;
}

// ---------------------------------------------------------------------------
// fused GEMM: out = act( aggr @ Wa + x2 @ Wx + bias )   (aggr is already mean)
//   A matrices are (M,256) row-major, W are (256,N) row-major.
//   64x64 tile per block, 256 threads, 4x4 micro-tile per thread.
//   act: 0 = relu, 1 = sigmoid
// ---------------------------------------------------------------------------
__global__ __launch_bounds__(256)
void gemm_fused_kernel(const float* __restrict__ aggr,
                       const float* __restrict__ x2,
                       const float* __restrict__ Wa,
                       const float* __restrict__ Wx,
                       const float* __restrict__ bias,
                       float* __restrict__ out,
                       int M, int N, int act) {
    // As[k][row]: stride 68 floats -> 16B-aligned ds_read_b128 at As[k][4*tx];
    // bank = (4k + 4tx) % 32 -> <=2-way aliasing (free on gfx950).
    __shared__ float As[64][68];

    const int tx = threadIdx.x & 15;   // row group (4 rows)
    const int ty = threadIdx.x >> 4;   // col group (4 cols)
    const int row0 = blockIdx.y * 64;
    const int col0 = blockIdx.x * 64;

    float acc[4][4] = {{0.f}};

    for (int p = 0; p < 2; ++p) {
        const float* __restrict__ A = p ? x2 : aggr;
        const float* __restrict__ W = p ? Wx : Wa;
        for (int kt = 0; kt < 4; ++kt) {
            // ---- stage A-tile (64 rows x 64 k), transposed into LDS ----
            #pragma unroll
            for (int it = 0; it < 4; ++it) {
                int idx = threadIdx.x + it * 256;
                int r  = idx >> 4;     // 0..63
                int kg = idx & 15;     // 0..15 (4 k's each)
                int row = row0 + r;
                if (row > M - 1) row = M - 1;   // tail clamp (stores guarded)
                float4 v = *(const float4*)(A + (size_t)row * 256 + kt * 64 + kg * 4);
                As[kg * 4 + 0][r] = v.x;
                As[kg * 4 + 1][r] = v.y;
                As[kg * 4 + 2][r] = v.z;
                As[kg * 4 + 3][r] = v.w;
            }
            __syncthreads();

            // ---- inner product over this k-tile ----
            #pragma unroll 8
            for (int k = 0; k < 64; ++k) {
                float4 a4 = *(const float4*)&As[k][tx * 4];
                float4 w4 = *(const float4*)(W + (size_t)(kt * 64 + k) * N + col0 + ty * 4);
                float av[4] = {a4.x, a4.y, a4.z, a4.w};
                float wv[4] = {w4.x, w4.y, w4.z, w4.w};
                #pragma unroll
                for (int i = 0; i < 4; ++i)
                    #pragma unroll
                    for (int j = 0; j < 4; ++j)
                        acc[i][j] += av[i] * wv[j];
            }
            __syncthreads();
        }
    }

    // ---- epilogue: bias + activation + store ----
    float4 b4 = *(const float4*)(bias + col0 + ty * 4);
    float bv[4] = {b4.x, b4.y, b4.z, b4.w};
    #pragma unroll
    for (int i = 0; i < 4; ++i) {
        int r = row0 + tx * 4 + i;
        if (r < M) {
            float o[4];
            #pragma unroll
            for (int j = 0; j < 4; ++j) {
                float v = acc[i][j] + bv[j];
                if (act == 0) v = fmaxf(v, 0.f);
                else          v = 1.0f / (1.0f + __expf(-v));
                o[j] = v;
            }
            *(float4*)(out + (size_t)r * N + col0 + ty * 4) = *(float4*)o;
        }
    }
}

// ---------------------------------------------------------------------------
// launch
// ---------------------------------------------------------------------------
extern "C" void kernel_launch(void* const* d_in, const int* in_sizes, int n_in,
                              void* d_out, int out_size, void* d_ws, size_t ws_size,
                              hipStream_t stream) {
    const float* x   = (const float*)d_in[0];
    const float* W1l = (const float*)d_in[1];
    const float* b1  = (const float*)d_in[2];
    const float* W1r = (const float*)d_in[3];
    const float* W2l = (const float*)d_in[4];
    const float* b2  = (const float*)d_in[5];
    const float* W2r = (const float*)d_in[6];
    const int* src1  = (const int*)d_in[7];
    const int* dst1  = (const int*)d_in[8];
    const int* src2  = (const int*)d_in[9];
    const int* dst2  = (const int*)d_in[10];
    float* out = (float*)d_out;

    // workspace layout (85.72 MB total; < R1-proven 92.36 MB)
    float* ws = (float*)d_ws;
    float* aggr1 = ws;                                   // N1*256 floats
    float* aggr2 = ws;                                   // aliases aggr1 (dead after GEMM1)
    float* h     = aggr1 + (size_t)N1_C * 256;           // N1*256 floats
    int* ip = (int*)(h + (size_t)N1_C * 256);
    int* deg1      = ip;               ip += N1_C;
    int* rowstart1 = ip;               ip += N1_C;
    int* cursor1   = ip;               ip += N1_C;
    int* perm1     = ip;               ip += E1_C;
    int* deg2      = ip;               ip += N2_C;
    int* rowstart2 = ip;               ip += N2_C;
    int* cursor2   = ip;               ip += N2_C;
    int* perm2     = ip;               ip += E2_C;

    // ---- build CSR for both layers (depends only on edge lists) ----
    zero_int_kernel<<<64, 256, 0, stream>>>(deg1, N1_C);
    zero_int_kernel<<<16, 256, 0, stream>>>(deg2, N2_C);
    hist_kernel<<<(E1_C + 255) / 256, 256, 0, stream>>>(dst1, deg1, E1_C, N1_C);
    hist_kernel<<<(E2_C + 255) / 256, 256, 0, stream>>>(dst2, deg2, E2_C, N2_C);
    scan_kernel<<<1, 256, 0, stream>>>(deg1, rowstart1, cursor1, N1_C);
    scan_kernel<<<1, 256, 0, stream>>>(deg2, rowstart2, cursor2, N2_C);
    permute_kernel<<<(E1_C + 255) / 256, 256, 0, stream>>>(src1, dst1, cursor1, perm1,
                                                           E1_C, N1_C);
    permute_kernel<<<(E2_C + 255) / 256, 256, 0, stream>>>(src2, dst2, cursor2, perm2,
                                                           E2_C, N2_C);

    // ---- layer 1: gather-mean then fused GEMM ----
    gather_mean_kernel<<<(N1_C + 3) / 4, 256, 0, stream>>>(x, rowstart1, cursor1, perm1,
                                                           aggr1, N1_C, E1_C, N0_C);
    {
        dim3 grid(D_HID_C / 64, N1_C / 64);  // (4, 625)
        gemm_fused_kernel<<<grid, 256, 0, stream>>>(aggr1, x, W1l, W1r, b1, h,
                                                    N1_C, D_HID_C, 0);
    }

    // ---- layer 2: gather-mean then fused GEMM (aggr2 aliases aggr1) ----
    gather_mean_kernel<<<(N2_C + 3) / 4, 256, 0, stream>>>(h, rowstart2, cursor2, perm2,
                                                           aggr2, N2_C, E2_C, N1_C);
    {
        dim3 grid(D_OUT_C / 64, (N2_C + 63) / 64);  // (2, 157)
        gemm_fused_kernel<<<grid, 256, 0, stream>>>(aggr2, h, W2l, W2r, b2, out,
                                                    N2_C, D_OUT_C, 1);
    }
}

// Round 7
// 535.348 us; speedup vs baseline: 6.2710x; 1.8554x over previous
//
#include <hip/hip_runtime.h>
#include <math.h>

// Problem constants (from reference)
#define N0_C  100000
#define N1_C  40000
#define N2_C  10000
#define E1_C  640000
#define E2_C  160000
#define D_IN_C  256
#define D_HID_C 256
#define D_OUT_C 128

typedef __attribute__((ext_vector_type(8))) short short8;     // 8 bf16 (4 VGPRs)
typedef __attribute__((ext_vector_type(4))) float float4v;    // MFMA acc

// round-to-nearest-even fp32 -> bf16 bits
__device__ __forceinline__ unsigned short f2bf(float f) {
    unsigned int u = __float_as_uint(f);
    return (unsigned short)((u + 0x7FFFu + ((u >> 16) & 1u)) >> 16);
}
__device__ __forceinline__ float bf2f(unsigned int h) {
    return __uint_as_float(h << 16);
}

// ---------------------------------------------------------------------------
// zero fill for int arrays
// ---------------------------------------------------------------------------
__global__ void zero_int_kernel(int* __restrict__ p, int n) {
    int i = blockIdx.x * blockDim.x + threadIdx.x;
    int stride = gridDim.x * blockDim.x;
    for (; i < n; i += stride) p[i] = 0;
}

// ---------------------------------------------------------------------------
// weight convert+transpose: Wt[n][k] = bf16(W[k][n]);  W is K x N row-major
// ---------------------------------------------------------------------------
__global__ void transpose_w_kernel(const float* __restrict__ W,
                                   unsigned short* __restrict__ Wt, int K, int N) {
    int id = blockIdx.x * blockDim.x + threadIdx.x;
    if (id >= K * N) return;
    int k = id / N, n = id - k * N;          // consecutive id -> consecutive n (coalesced read)
    Wt[n * K + k] = f2bf(W[id]);
}

// ---------------------------------------------------------------------------
// fp32 -> bf16 bulk convert (float4 in, 4xbf16 packed u64 out)
// ---------------------------------------------------------------------------
__global__ void convert_bf16_kernel(const float* __restrict__ src,
                                    unsigned short* __restrict__ dst, int n4) {
    int i = blockIdx.x * blockDim.x + threadIdx.x;
    int stride = gridDim.x * blockDim.x;
    for (; i < n4; i += stride) {
        float4 v = ((const float4*)src)[i];
        unsigned long long u = (unsigned long long)f2bf(v.x)
                             | ((unsigned long long)f2bf(v.y) << 16)
                             | ((unsigned long long)f2bf(v.z) << 32)
                             | ((unsigned long long)f2bf(v.w) << 48);
        ((unsigned long long*)dst)[i] = u;
    }
}

// ---------------------------------------------------------------------------
// CSR build: histogram / scan / permute (all indices clamped -> cannot fault)
// ---------------------------------------------------------------------------
__global__ void hist_kernel(const int* __restrict__ dst, int* __restrict__ deg,
                            int E, int n) {
    int e = blockIdx.x * blockDim.x + threadIdx.x;
    if (e >= E) return;
    int d = min(max(dst[e], 0), n - 1);
    atomicAdd(&deg[d], 1);
}

__global__ __launch_bounds__(256)
void scan_kernel(const int* __restrict__ deg, int* __restrict__ rowstart,
                 int* __restrict__ cursor, int n) {
    __shared__ int sums[256];
    const int chunk = (n + 255) / 256;
    const int b = threadIdx.x * chunk;
    const int e = min(b + chunk, n);
    int s = 0;
    for (int i = b; i < e; ++i) s += deg[i];
    sums[threadIdx.x] = s;
    __syncthreads();
    for (int off = 1; off < 256; off <<= 1) {
        int t = (threadIdx.x >= off) ? sums[threadIdx.x - off] : 0;
        __syncthreads();
        sums[threadIdx.x] += t;
        __syncthreads();
    }
    int run = (threadIdx.x == 0) ? 0 : sums[threadIdx.x - 1];
    for (int i = b; i < e; ++i) {
        rowstart[i] = run;
        cursor[i]   = run;
        run += deg[i];
    }
}

__global__ void permute_kernel(const int* __restrict__ src, const int* __restrict__ dst,
                               int* __restrict__ cursor, int* __restrict__ perm,
                               int E, int n) {
    int e = blockIdx.x * blockDim.x + threadIdx.x;
    if (e >= E) return;
    int d = min(max(dst[e], 0), n - 1);
    int pos = atomicAdd(&cursor[d], 1);
    pos = min(max(pos, 0), E - 1);
    perm[pos] = src[e];
}

// ---------------------------------------------------------------------------
// gather-mean, fp32 input -> bf16 output. One wave per node, lane = 4 channels.
// ---------------------------------------------------------------------------
__global__ __launch_bounds__(256)
void gather_mean_f32_kernel(const float* __restrict__ feat,
                            const int* __restrict__ rowstart,
                            const int* __restrict__ cursor,
                            const int* __restrict__ perm,
                            unsigned short* __restrict__ aggr,
                            int n, int E, int nfeat) {
    int node = blockIdx.x * 4 + (threadIdx.x >> 6);
    int lane = threadIdx.x & 63;
    if (node >= n) return;
    int beg = min(max(rowstart[node], 0), E);
    int end = min(max(cursor[node], beg), E);
    float4 acc = make_float4(0.f, 0.f, 0.f, 0.f);
    int i = beg;
    for (; i + 4 <= end; i += 4) {
        int s0 = min(max(perm[i + 0], 0), nfeat - 1);
        int s1 = min(max(perm[i + 1], 0), nfeat - 1);
        int s2 = min(max(perm[i + 2], 0), nfeat - 1);
        int s3 = min(max(perm[i + 3], 0), nfeat - 1);
        float4 v0 = *(const float4*)(feat + (size_t)s0 * 256 + lane * 4);
        float4 v1 = *(const float4*)(feat + (size_t)s1 * 256 + lane * 4);
        float4 v2 = *(const float4*)(feat + (size_t)s2 * 256 + lane * 4);
        float4 v3 = *(const float4*)(feat + (size_t)s3 * 256 + lane * 4);
        acc.x += v0.x + v1.x + v2.x + v3.x;
        acc.y += v0.y + v1.y + v2.y + v3.y;
        acc.z += v0.z + v1.z + v2.z + v3.z;
        acc.w += v0.w + v1.w + v2.w + v3.w;
    }
    for (; i < end; ++i) {
        int s = min(max(perm[i], 0), nfeat - 1);
        float4 v = *(const float4*)(feat + (size_t)s * 256 + lane * 4);
        acc.x += v.x; acc.y += v.y; acc.z += v.z; acc.w += v.w;
    }
    float inv = (end > beg) ? 1.0f / (float)(end - beg) : 0.0f;
    unsigned long long u = (unsigned long long)f2bf(acc.x * inv)
                         | ((unsigned long long)f2bf(acc.y * inv) << 16)
                         | ((unsigned long long)f2bf(acc.z * inv) << 32)
                         | ((unsigned long long)f2bf(acc.w * inv) << 48);
    *(unsigned long long*)(aggr + (size_t)node * 256 + lane * 4) = u;
}

// ---------------------------------------------------------------------------
// gather-mean, bf16 input -> bf16 output (layer 2, reads h)
// ---------------------------------------------------------------------------
__global__ __launch_bounds__(256)
void gather_mean_bf16_kernel(const unsigned short* __restrict__ feat,
                             const int* __restrict__ rowstart,
                             const int* __restrict__ cursor,
                             const int* __restrict__ perm,
                             unsigned short* __restrict__ aggr,
                             int n, int E, int nfeat) {
    int node = blockIdx.x * 4 + (threadIdx.x >> 6);
    int lane = threadIdx.x & 63;
    if (node >= n) return;
    int beg = min(max(rowstart[node], 0), E);
    int end = min(max(cursor[node], beg), E);
    float a0 = 0.f, a1 = 0.f, a2 = 0.f, a3 = 0.f;
    int i = beg;
    for (; i + 2 <= end; i += 2) {
        int s0 = min(max(perm[i + 0], 0), nfeat - 1);
        int s1 = min(max(perm[i + 1], 0), nfeat - 1);
        unsigned long long u0 = *(const unsigned long long*)(feat + (size_t)s0 * 256 + lane * 4);
        unsigned long long u1 = *(const unsigned long long*)(feat + (size_t)s1 * 256 + lane * 4);
        a0 += bf2f((unsigned int)(u0      ) & 0xFFFFu) + bf2f((unsigned int)(u1      ) & 0xFFFFu);
        a1 += bf2f((unsigned int)(u0 >> 16) & 0xFFFFu) + bf2f((unsigned int)(u1 >> 16) & 0xFFFFu);
        a2 += bf2f((unsigned int)(u0 >> 32) & 0xFFFFu) + bf2f((unsigned int)(u1 >> 32) & 0xFFFFu);
        a3 += bf2f((unsigned int)(u0 >> 48) & 0xFFFFu) + bf2f((unsigned int)(u1 >> 48) & 0xFFFFu);
    }
    for (; i < end; ++i) {
        int s = min(max(perm[i], 0), nfeat - 1);
        unsigned long long u = *(const unsigned long long*)(feat + (size_t)s * 256 + lane * 4);
        a0 += bf2f((unsigned int)(u      ) & 0xFFFFu);
        a1 += bf2f((unsigned int)(u >> 16) & 0xFFFFu);
        a2 += bf2f((unsigned int)(u >> 32) & 0xFFFFu);
        a3 += bf2f((unsigned int)(u >> 48) & 0xFFFFu);
    }
    float inv = (end > beg) ? 1.0f / (float)(end - beg) : 0.0f;
    unsigned long long u = (unsigned long long)f2bf(a0 * inv)
                         | ((unsigned long long)f2bf(a1 * inv) << 16)
                         | ((unsigned long long)f2bf(a2 * inv) << 32)
                         | ((unsigned long long)f2bf(a3 * inv) << 48);
    *(unsigned long long*)(aggr + (size_t)node * 256 + lane * 4) = u;
}

// ---------------------------------------------------------------------------
// MFMA GEMM: out = act( A0 @ Wt0^T + A1 @ Wt1^T + bias )
//   A0/A1: (M x 256) bf16 row-major. Wt0/Wt1: (N x 256) bf16 (pre-transposed).
//   128x128 tile, 4 waves (2x2), each wave 4x4 MFMA tiles of 16x16x32.
//   act 0: relu -> bf16 out_bf;  act 1: sigmoid -> fp32 out_f.
// Fragment layouts (m89/m120-verified): A[m=lane&15][k=(lane>>4)*8+j],
// B[k=(lane>>4)*8+j][n=lane&15], D: col=lane&15, row=(lane>>4)*4+reg.
// ---------------------------------------------------------------------------
__global__ __launch_bounds__(256)
void mfma_gemm_kernel(const unsigned short* __restrict__ A0,
                      const unsigned short* __restrict__ A1,
                      const unsigned short* __restrict__ Wt0,
                      const unsigned short* __restrict__ Wt1,
                      const float* __restrict__ bias,
                      unsigned short* __restrict__ out_bf,
                      float* __restrict__ out_f,
                      int M, int N, int act) {
    // +8 pad: row pitch 144 B -> frag reads/writes alias <=2-way (free, m136)
    __shared__ unsigned short As[128][72];
    __shared__ unsigned short Bs[128][72];

    const int tid  = threadIdx.x;
    const int lane = tid & 63;
    const int wid  = tid >> 6;
    const int wm   = wid & 1;          // wave row (0..1)
    const int wn   = wid >> 1;         // wave col (0..1)
    const int lr   = lane & 15;
    const int kq   = lane >> 4;        // 0..3
    const int row0 = blockIdx.y * 128;
    const int col0 = blockIdx.x * 128;

    // staging map: thread -> (row sr, col-seg sc); 8 threads cover one 64-col row
    const int sr = tid >> 3;           // 0..31
    const int sc = (tid & 7) * 8;      // 0..56

    float4v acc[4][4];
    #pragma unroll
    for (int a = 0; a < 4; ++a)
        #pragma unroll
        for (int b = 0; b < 4; ++b)
            #pragma unroll
            for (int c = 0; c < 4; ++c) acc[a][b][c] = 0.f;

    for (int p = 0; p < 2; ++p) {
        const unsigned short* __restrict__ A  = p ? A1  : A0;
        const unsigned short* __restrict__ Wt = p ? Wt1 : Wt0;
        for (int kt = 0; kt < 4; ++kt) {
            const int k0 = kt * 64;
            __syncthreads();           // previous tile's reads done before overwrite
            #pragma unroll
            for (int rr = 0; rr < 128; rr += 32) {
                int row = row0 + sr + rr;
                if (row > M - 1) row = M - 1;            // tail clamp (stores guarded)
                *(short8*)&As[sr + rr][sc] =
                    *(const short8*)(A + (size_t)row * 256 + k0 + sc);
                int n = col0 + sr + rr;                  // N is a multiple of 128
                *(short8*)&Bs[sr + rr][sc] =
                    *(const short8*)(Wt + (size_t)n * 256 + k0 + sc);
            }
            __syncthreads();
            #pragma unroll
            for (int ks = 0; ks < 64; ks += 32) {
                short8 af[4], bfr[4];
                #pragma unroll
                for (int t = 0; t < 4; ++t) {
                    af[t]  = *(const short8*)&As[wm * 64 + t * 16 + lr][ks + kq * 8];
                    bfr[t] = *(const short8*)&Bs[wn * 64 + t * 16 + lr][ks + kq * 8];
                }
                #pragma unroll
                for (int ar = 0; ar < 4; ++ar)
                    #pragma unroll
                    for (int bc = 0; bc < 4; ++bc)
                        acc[ar][bc] = __builtin_amdgcn_mfma_f32_16x16x32_bf16(
                            af[ar], bfr[bc], acc[ar][bc], 0, 0, 0);
            }
        }
    }

    // epilogue: bias + activation + store (D: col=lane&15, row=kq*4+i)
    #pragma unroll
    for (int bc = 0; bc < 4; ++bc) {
        int col = col0 + wn * 64 + bc * 16 + lr;
        float bv = bias[col];
        #pragma unroll
        for (int ar = 0; ar < 4; ++ar) {
            int rowb = row0 + wm * 64 + ar * 16 + kq * 4;
            #pragma unroll
            for (int i = 0; i < 4; ++i) {
                int row = rowb + i;
                if (row < M) {
                    float v = acc[ar][bc][i] + bv;
                    if (act == 0)
                        out_bf[(size_t)row * N + col] = f2bf(fmaxf(v, 0.f));
                    else
                        out_f[(size_t)row * N + col] = 1.0f / (1.0f + __expf(-v));
                }
            }
        }
    }
}

// ---------------------------------------------------------------------------
// launch
// ---------------------------------------------------------------------------
extern "C" void kernel_launch(void* const* d_in, const int* in_sizes, int n_in,
                              void* d_out, int out_size, void* d_ws, size_t ws_size,
                              hipStream_t stream) {
    const float* x   = (const float*)d_in[0];
    const float* W1l = (const float*)d_in[1];
    const float* b1  = (const float*)d_in[2];
    const float* W1r = (const float*)d_in[3];
    const float* W2l = (const float*)d_in[4];
    const float* b2  = (const float*)d_in[5];
    const float* W2r = (const float*)d_in[6];
    const int* src1  = (const int*)d_in[7];
    const int* dst1  = (const int*)d_in[8];
    const int* src2  = (const int*)d_in[9];
    const int* dst2  = (const int*)d_in[10];
    float* out = (float*)d_out;

    // workspace layout: bf16 arrays first (all 16B-multiple sizes), then ints.
    // Total ~71.7 MB < R1-proven 92.4 MB budget.
    unsigned short* us = (unsigned short*)d_ws;
    unsigned short* aggr1 = us;                          us += (size_t)N1_C * 256;
    unsigned short* xb    = us;                          us += (size_t)N1_C * 256;
    unsigned short* h     = us;                          us += (size_t)N1_C * 256;
    unsigned short* aggr2 = us;                          us += (size_t)N2_C * 256;
    unsigned short* wt1l  = us;                          us += 256 * 256;
    unsigned short* wt1r  = us;                          us += 256 * 256;
    unsigned short* wt2l  = us;                          us += 128 * 256;
    unsigned short* wt2r  = us;                          us += 128 * 256;
    int* ip = (int*)us;
    int* deg1      = ip;               ip += N1_C;       // deg1+deg2 adjacent (one zero pass)
    int* deg2      = ip;               ip += N2_C;
    int* rowstart1 = ip;               ip += N1_C;
    int* cursor1   = ip;               ip += N1_C;
    int* perm1     = ip;               ip += E1_C;
    int* rowstart2 = ip;               ip += N2_C;
    int* cursor2   = ip;               ip += N2_C;
    int* perm2     = ip;               ip += E2_C;

    // ---- weight transpose + x bf16 convert (independent of edges) ----
    transpose_w_kernel<<<(256 * 256 + 255) / 256, 256, 0, stream>>>(W1l, wt1l, 256, 256);
    transpose_w_kernel<<<(256 * 256 + 255) / 256, 256, 0, stream>>>(W1r, wt1r, 256, 256);
    transpose_w_kernel<<<(256 * 128 + 255) / 256, 256, 0, stream>>>(W2l, wt2l, 256, 128);
    transpose_w_kernel<<<(256 * 128 + 255) / 256, 256, 0, stream>>>(W2r, wt2r, 256, 128);
    convert_bf16_kernel<<<4096, 256, 0, stream>>>(x, xb, (N1_C * 256) / 4);

    // ---- build CSR for both layers ----
    zero_int_kernel<<<64, 256, 0, stream>>>(deg1, N1_C + N2_C);
    hist_kernel<<<(E1_C + 255) / 256, 256, 0, stream>>>(dst1, deg1, E1_C, N1_C);
    hist_kernel<<<(E2_C + 255) / 256, 256, 0, stream>>>(dst2, deg2, E2_C, N2_C);
    scan_kernel<<<1, 256, 0, stream>>>(deg1, rowstart1, cursor1, N1_C);
    scan_kernel<<<1, 256, 0, stream>>>(deg2, rowstart2, cursor2, N2_C);
    permute_kernel<<<(E1_C + 255) / 256, 256, 0, stream>>>(src1, dst1, cursor1, perm1,
                                                           E1_C, N1_C);
    permute_kernel<<<(E2_C + 255) / 256, 256, 0, stream>>>(src2, dst2, cursor2, perm2,
                                                           E2_C, N2_C);

    // ---- layer 1: gather-mean (fp32 x -> bf16 aggr1) then MFMA GEMM -> bf16 h ----
    gather_mean_f32_kernel<<<(N1_C + 3) / 4, 256, 0, stream>>>(x, rowstart1, cursor1,
                                                               perm1, aggr1,
                                                               N1_C, E1_C, N0_C);
    {
        dim3 grid(D_HID_C / 128, (N1_C + 127) / 128);   // (2, 313)
        mfma_gemm_kernel<<<grid, 256, 0, stream>>>(aggr1, xb, wt1l, wt1r, b1,
                                                   h, (float*)nullptr,
                                                   N1_C, D_HID_C, 0);
    }

    // ---- layer 2: gather-mean (bf16 h -> bf16 aggr2) then MFMA GEMM -> fp32 out ----
    gather_mean_bf16_kernel<<<(N2_C + 3) / 4, 256, 0, stream>>>(h, rowstart2, cursor2,
                                                                perm2, aggr2,
                                                                N2_C, E2_C, N1_C);
    {
        dim3 grid(D_OUT_C / 128, (N2_C + 127) / 128);   // (1, 79)
        mfma_gemm_kernel<<<grid, 256, 0, stream>>>(aggr2, h, wt2l, wt2r, b2,
                                                   (unsigned short*)nullptr, out,
                                                   N2_C, D_OUT_C, 1);
    }
}

// Round 8
// 474.096 us; speedup vs baseline: 7.0812x; 1.1292x over previous
//
#include <hip/hip_runtime.h>
#include <math.h>

// Problem constants (from reference)
#define N0_C  100000
#define N1_C  40000
#define N2_C  10000
#define E1_C  640000
#define E2_C  160000
#define D_IN_C  256
#define D_HID_C 256
#define D_OUT_C 128

typedef __attribute__((ext_vector_type(8))) short short8;     // 8 bf16 (4 VGPRs)
typedef __attribute__((ext_vector_type(4))) float float4v;    // MFMA acc

// round-to-nearest-even fp32 -> bf16 bits
__device__ __forceinline__ unsigned short f2bf(float f) {
    unsigned int u = __float_as_uint(f);
    return (unsigned short)((u + 0x7FFFu + ((u >> 16) & 1u)) >> 16);
}
__device__ __forceinline__ float bf2f(unsigned int h) {
    return __uint_as_float(h << 16);
}

// ---------------------------------------------------------------------------
// zero fill for int arrays
// ---------------------------------------------------------------------------
__global__ void zero_int_kernel(int* __restrict__ p, int n) {
    int i = blockIdx.x * blockDim.x + threadIdx.x;
    int stride = gridDim.x * blockDim.x;
    for (; i < n; i += stride) p[i] = 0;
}

// ---------------------------------------------------------------------------
// fp32 -> bf16 bulk convert of x (float4 in, 4xbf16 packed u64 out)
// ---------------------------------------------------------------------------
__global__ void convert_x_kernel(const float* __restrict__ src,
                                 unsigned short* __restrict__ dst, int n4) {
    int i = blockIdx.x * blockDim.x + threadIdx.x;
    int stride = gridDim.x * blockDim.x;
    for (; i < n4; i += stride) {
        float4 v = ((const float4*)src)[i];
        unsigned long long u = (unsigned long long)f2bf(v.x)
                             | ((unsigned long long)f2bf(v.y) << 16)
                             | ((unsigned long long)f2bf(v.z) << 32)
                             | ((unsigned long long)f2bf(v.w) << 48);
        ((unsigned long long*)dst)[i] = u;
    }
}

// ---------------------------------------------------------------------------
// all 4 weight transposes in one launch: Wt[n][256+k] = bf16(W[k][n])
// id ranges: [0,64K) W1l | [64K,128K) W1r | [128K,160K) W2l | [160K,192K) W2r
// ---------------------------------------------------------------------------
__global__ void transpose_all_w_kernel(const float* __restrict__ W1l,
                                       const float* __restrict__ W1r,
                                       const float* __restrict__ W2l,
                                       const float* __restrict__ W2r,
                                       unsigned short* __restrict__ wt1l,
                                       unsigned short* __restrict__ wt1r,
                                       unsigned short* __restrict__ wt2l,
                                       unsigned short* __restrict__ wt2r) {
    int id = blockIdx.x * blockDim.x + threadIdx.x;
    if (id >= 196608) return;
    const float* W; unsigned short* Wt; int N; int off;
    if (id < 65536)       { W = W1l; Wt = wt1l; N = 256; off = id; }
    else if (id < 131072) { W = W1r; Wt = wt1r; N = 256; off = id - 65536; }
    else if (id < 163840) { W = W2l; Wt = wt2l; N = 128; off = id - 131072; }
    else                  { W = W2r; Wt = wt2r; N = 128; off = id - 163840; }
    int k = off / N, n = off - k * N;        // consecutive off -> consecutive n (coalesced)
    Wt[n * 256 + k] = f2bf(W[off]);
}

// ---------------------------------------------------------------------------
// CSR build, both layers fused (all indices clamped -> cannot fault)
// ---------------------------------------------------------------------------
__global__ void hist_both_kernel(const int* __restrict__ dst1,
                                 const int* __restrict__ dst2,
                                 int* __restrict__ deg1, int* __restrict__ deg2) {
    int e = blockIdx.x * blockDim.x + threadIdx.x;
    if (e < E1_C) {
        int d = min(max(dst1[e], 0), N1_C - 1);
        atomicAdd(&deg1[d], 1);
    } else if (e < E1_C + E2_C) {
        int d = min(max(dst2[e - E1_C], 0), N2_C - 1);
        atomicAdd(&deg2[d], 1);
    }
}

__global__ __launch_bounds__(256)
void scan_both_kernel(const int* __restrict__ deg1, int* __restrict__ rs1,
                      int* __restrict__ cur1,
                      const int* __restrict__ deg2, int* __restrict__ rs2,
                      int* __restrict__ cur2) {
    const int* deg = blockIdx.x ? deg2 : deg1;
    int* rowstart  = blockIdx.x ? rs2  : rs1;
    int* cursor    = blockIdx.x ? cur2 : cur1;
    const int n    = blockIdx.x ? N2_C : N1_C;
    __shared__ int sums[256];
    const int chunk = (n + 255) / 256;
    const int b = threadIdx.x * chunk;
    const int e = min(b + chunk, n);
    int s = 0;
    for (int i = b; i < e; ++i) s += deg[i];
    sums[threadIdx.x] = s;
    __syncthreads();
    for (int off = 1; off < 256; off <<= 1) {
        int t = (threadIdx.x >= off) ? sums[threadIdx.x - off] : 0;
        __syncthreads();
        sums[threadIdx.x] += t;
        __syncthreads();
    }
    int run = (threadIdx.x == 0) ? 0 : sums[threadIdx.x - 1];
    for (int i = b; i < e; ++i) {
        rowstart[i] = run;
        cursor[i]   = run;
        run += deg[i];
    }
}

__global__ void permute_both_kernel(const int* __restrict__ src1,
                                    const int* __restrict__ dst1,
                                    int* __restrict__ cur1, int* __restrict__ perm1,
                                    const int* __restrict__ src2,
                                    const int* __restrict__ dst2,
                                    int* __restrict__ cur2, int* __restrict__ perm2) {
    int e = blockIdx.x * blockDim.x + threadIdx.x;
    if (e < E1_C) {
        int d = min(max(dst1[e], 0), N1_C - 1);
        int pos = atomicAdd(&cur1[d], 1);
        pos = min(max(pos, 0), E1_C - 1);
        perm1[pos] = src1[e];
    } else if (e < E1_C + E2_C) {
        int e2 = e - E1_C;
        int d = min(max(dst2[e2], 0), N2_C - 1);
        int pos = atomicAdd(&cur2[d], 1);
        pos = min(max(pos, 0), E2_C - 1);
        perm2[pos] = src2[e2];
    }
}

// ---------------------------------------------------------------------------
// gather-mean, bf16 in -> bf16 out. One wave per node, lane = 4 channels (u64).
// ---------------------------------------------------------------------------
__global__ __launch_bounds__(256)
void gather_mean_bf16_kernel(const unsigned short* __restrict__ feat,
                             const int* __restrict__ rowstart,
                             const int* __restrict__ cursor,
                             const int* __restrict__ perm,
                             unsigned short* __restrict__ aggr,
                             int n, int E, int nfeat) {
    int node = blockIdx.x * 4 + (threadIdx.x >> 6);
    int lane = threadIdx.x & 63;
    if (node >= n) return;
    int beg = min(max(rowstart[node], 0), E);
    int end = min(max(cursor[node], beg), E);
    float a0 = 0.f, a1 = 0.f, a2 = 0.f, a3 = 0.f;
    int i = beg;
    for (; i + 4 <= end; i += 4) {
        int s0 = min(max(perm[i + 0], 0), nfeat - 1);
        int s1 = min(max(perm[i + 1], 0), nfeat - 1);
        int s2 = min(max(perm[i + 2], 0), nfeat - 1);
        int s3 = min(max(perm[i + 3], 0), nfeat - 1);
        unsigned long long u0 = *(const unsigned long long*)(feat + (size_t)s0 * 256 + lane * 4);
        unsigned long long u1 = *(const unsigned long long*)(feat + (size_t)s1 * 256 + lane * 4);
        unsigned long long u2 = *(const unsigned long long*)(feat + (size_t)s2 * 256 + lane * 4);
        unsigned long long u3 = *(const unsigned long long*)(feat + (size_t)s3 * 256 + lane * 4);
        a0 += bf2f((unsigned int)(u0      ) & 0xFFFFu) + bf2f((unsigned int)(u1      ) & 0xFFFFu)
            + bf2f((unsigned int)(u2      ) & 0xFFFFu) + bf2f((unsigned int)(u3      ) & 0xFFFFu);
        a1 += bf2f((unsigned int)(u0 >> 16) & 0xFFFFu) + bf2f((unsigned int)(u1 >> 16) & 0xFFFFu)
            + bf2f((unsigned int)(u2 >> 16) & 0xFFFFu) + bf2f((unsigned int)(u3 >> 16) & 0xFFFFu);
        a2 += bf2f((unsigned int)(u0 >> 32) & 0xFFFFu) + bf2f((unsigned int)(u1 >> 32) & 0xFFFFu)
            + bf2f((unsigned int)(u2 >> 32) & 0xFFFFu) + bf2f((unsigned int)(u3 >> 32) & 0xFFFFu);
        a3 += bf2f((unsigned int)(u0 >> 48)          ) + bf2f((unsigned int)(u1 >> 48)          )
            + bf2f((unsigned int)(u2 >> 48)          ) + bf2f((unsigned int)(u3 >> 48)          );
    }
    for (; i < end; ++i) {
        int s = min(max(perm[i], 0), nfeat - 1);
        unsigned long long u = *(const unsigned long long*)(feat + (size_t)s * 256 + lane * 4);
        a0 += bf2f((unsigned int)(u      ) & 0xFFFFu);
        a1 += bf2f((unsigned int)(u >> 16) & 0xFFFFu);
        a2 += bf2f((unsigned int)(u >> 32) & 0xFFFFu);
        a3 += bf2f((unsigned int)(u >> 48)          );
    }
    float inv = (end > beg) ? 1.0f / (float)(end - beg) : 0.0f;
    unsigned long long u = (unsigned long long)f2bf(a0 * inv)
                         | ((unsigned long long)f2bf(a1 * inv) << 16)
                         | ((unsigned long long)f2bf(a2 * inv) << 32)
                         | ((unsigned long long)f2bf(a3 * inv) << 48);
    *(unsigned long long*)(aggr + (size_t)node * 256 + lane * 4) = u;
}

// ---------------------------------------------------------------------------
// layer-1 MFMA GEMM, single column block: h = relu( A0@Wt0^T + A1@Wt1^T + b )
//   128 rows x 256 cols per block, 512 threads (8 waves, 2x4), grid (313).
//   out_bf ALIASES A1 (h overwrites xb in place): each block writes only the
//   rows it alone reads, and the epilogue strictly follows all K-loop reads.
//   NOTE: A0/A1/out_bf intentionally NOT __restrict__ (alias).
// ---------------------------------------------------------------------------
__global__ __launch_bounds__(512)
void mfma_gemm1_kernel(const unsigned short* A0,
                       const unsigned short* A1,
                       const unsigned short* __restrict__ Wt0,
                       const unsigned short* __restrict__ Wt1,
                       const float* __restrict__ bias,
                       unsigned short* out_bf,
                       int M) {
    // +8 pad: row pitch 144 B (16B-aligned) -> <=2-way bank aliasing (free)
    __shared__ unsigned short As[128][72];
    __shared__ unsigned short Bs[256][72];

    const int tid  = threadIdx.x;
    const int lane = tid & 63;
    const int wid  = tid >> 6;         // 0..7
    const int wm   = wid & 1;          // wave row (0..1) -> 64-row half
    const int wn   = wid >> 1;         // wave col (0..3) -> 64-col quarter
    const int lr   = lane & 15;
    const int kq   = lane >> 4;        // 0..3
    const int row0 = blockIdx.x * 128;

    float4v acc[4][4];
    #pragma unroll
    for (int a = 0; a < 4; ++a)
        #pragma unroll
        for (int b = 0; b < 4; ++b)
            #pragma unroll
            for (int c = 0; c < 4; ++c) acc[a][b][c] = 0.f;

    for (int p = 0; p < 2; ++p) {
        const unsigned short* A  = p ? A1  : A0;
        const unsigned short* __restrict__ Wt = p ? Wt1 : Wt0;
        for (int kt = 0; kt < 4; ++kt) {
            const int k0 = kt * 64;
            __syncthreads();
            // As: 128 rows x 8 col-segs = 1024 short8 slots, 2/thread
            #pragma unroll
            for (int i = 0; i < 2; ++i) {
                int idx = tid + i * 512;
                int r = idx >> 3, sc = (idx & 7) * 8;
                int row = row0 + r;
                if (row > M - 1) row = M - 1;   // tail clamp (stores guarded)
                *(short8*)&As[r][sc] = *(const short8*)(A + (size_t)row * 256 + k0 + sc);
            }
            // Bs: 256 rows x 8 col-segs = 2048 short8 slots, 4/thread
            #pragma unroll
            for (int i = 0; i < 4; ++i) {
                int idx = tid + i * 512;
                int r = idx >> 3, sc = (idx & 7) * 8;
                *(short8*)&Bs[r][sc] = *(const short8*)(Wt + (size_t)r * 256 + k0 + sc);
            }
            __syncthreads();
            #pragma unroll
            for (int ks = 0; ks < 64; ks += 32) {
                short8 af[4], bfr[4];
                #pragma unroll
                for (int t = 0; t < 4; ++t) {
                    af[t]  = *(const short8*)&As[wm * 64 + t * 16 + lr][ks + kq * 8];
                    bfr[t] = *(const short8*)&Bs[wn * 64 + t * 16 + lr][ks + kq * 8];
                }
                #pragma unroll
                for (int ar = 0; ar < 4; ++ar)
                    #pragma unroll
                    for (int bc = 0; bc < 4; ++bc)
                        acc[ar][bc] = __builtin_amdgcn_mfma_f32_16x16x32_bf16(
                            af[ar], bfr[bc], acc[ar][bc], 0, 0, 0);
            }
        }
    }

    // epilogue: bias + relu -> bf16 (D: col=lane&15, row=kq*4+i)
    #pragma unroll
    for (int bc = 0; bc < 4; ++bc) {
        int col = wn * 64 + bc * 16 + lr;
        float bv = bias[col];
        #pragma unroll
        for (int ar = 0; ar < 4; ++ar) {
            int rowb = row0 + wm * 64 + ar * 16 + kq * 4;
            #pragma unroll
            for (int i = 0; i < 4; ++i) {
                int row = rowb + i;
                if (row < M)
                    out_bf[(size_t)row * 256 + col] = f2bf(fmaxf(acc[ar][bc][i] + bv, 0.f));
            }
        }
    }
}

// ---------------------------------------------------------------------------
// layer-2 MFMA GEMM (R7 kernel): out = sigmoid( A0@Wt0^T + A1@Wt1^T + b )
//   128x128 tile, 256 threads (4 waves, 2x2), grid (1, 79). fp32 output.
// ---------------------------------------------------------------------------
__global__ __launch_bounds__(256)
void mfma_gemm2_kernel(const unsigned short* __restrict__ A0,
                       const unsigned short* __restrict__ A1,
                       const unsigned short* __restrict__ Wt0,
                       const unsigned short* __restrict__ Wt1,
                       const float* __restrict__ bias,
                       float* __restrict__ out_f,
                       int M, int N) {
    __shared__ unsigned short As[128][72];
    __shared__ unsigned short Bs[128][72];

    const int tid  = threadIdx.x;
    const int lane = tid & 63;
    const int wid  = tid >> 6;
    const int wm   = wid & 1;
    const int wn   = wid >> 1;
    const int lr   = lane & 15;
    const int kq   = lane >> 4;
    const int row0 = blockIdx.y * 128;
    const int col0 = blockIdx.x * 128;

    const int sr = tid >> 3;
    const int sc = (tid & 7) * 8;

    float4v acc[4][4];
    #pragma unroll
    for (int a = 0; a < 4; ++a)
        #pragma unroll
        for (int b = 0; b < 4; ++b)
            #pragma unroll
            for (int c = 0; c < 4; ++c) acc[a][b][c] = 0.f;

    for (int p = 0; p < 2; ++p) {
        const unsigned short* __restrict__ A  = p ? A1  : A0;
        const unsigned short* __restrict__ Wt = p ? Wt1 : Wt0;
        for (int kt = 0; kt < 4; ++kt) {
            const int k0 = kt * 64;
            __syncthreads();
            #pragma unroll
            for (int rr = 0; rr < 128; rr += 32) {
                int row = row0 + sr + rr;
                if (row > M - 1) row = M - 1;
                *(short8*)&As[sr + rr][sc] =
                    *(const short8*)(A + (size_t)row * 256 + k0 + sc);
                int n = col0 + sr + rr;          // N multiple of 128
                *(short8*)&Bs[sr + rr][sc] =
                    *(const short8*)(Wt + (size_t)n * 256 + k0 + sc);
            }
            __syncthreads();
            #pragma unroll
            for (int ks = 0; ks < 64; ks += 32) {
                short8 af[4], bfr[4];
                #pragma unroll
                for (int t = 0; t < 4; ++t) {
                    af[t]  = *(const short8*)&As[wm * 64 + t * 16 + lr][ks + kq * 8];
                    bfr[t] = *(const short8*)&Bs[wn * 64 + t * 16 + lr][ks + kq * 8];
                }
                #pragma unroll
                for (int ar = 0; ar < 4; ++ar)
                    #pragma unroll
                    for (int bc = 0; bc < 4; ++bc)
                        acc[ar][bc] = __builtin_amdgcn_mfma_f32_16x16x32_bf16(
                            af[ar], bfr[bc], acc[ar][bc], 0, 0, 0);
            }
        }
    }

    #pragma unroll
    for (int bc = 0; bc < 4; ++bc) {
        int col = col0 + wn * 64 + bc * 16 + lr;
        float bv = bias[col];
        #pragma unroll
        for (int ar = 0; ar < 4; ++ar) {
            int rowb = row0 + wm * 64 + ar * 16 + kq * 4;
            #pragma unroll
            for (int i = 0; i < 4; ++i) {
                int row = rowb + i;
                if (row < M)
                    out_f[(size_t)row * N + col] =
                        1.0f / (1.0f + __expf(-(acc[ar][bc][i] + bv)));
            }
        }
    }
}

// ---------------------------------------------------------------------------
// launch
// ---------------------------------------------------------------------------
extern "C" void kernel_launch(void* const* d_in, const int* in_sizes, int n_in,
                              void* d_out, int out_size, void* d_ws, size_t ws_size,
                              hipStream_t stream) {
    const float* x   = (const float*)d_in[0];
    const float* W1l = (const float*)d_in[1];
    const float* b1  = (const float*)d_in[2];
    const float* W1r = (const float*)d_in[3];
    const float* W2l = (const float*)d_in[4];
    const float* b2  = (const float*)d_in[5];
    const float* W2r = (const float*)d_in[6];
    const int* src1  = (const int*)d_in[7];
    const int* dst1  = (const int*)d_in[8];
    const int* src2  = (const int*)d_in[9];
    const int* dst2  = (const int*)d_in[10];
    float* out = (float*)d_out;

    // workspace layout (~75.9 MB, well under the R1-proven 92.4 MB budget):
    //   xb    : bf16 x, all N0 rows. gemm1 writes h IN PLACE over rows [0,N1).
    //   aggr1 : bf16 N1 rows; aggr2 aliases its first N2 rows (aggr1 dead then).
    unsigned short* us = (unsigned short*)d_ws;
    unsigned short* xb    = us;                          us += (size_t)N0_C * 256;
    unsigned short* h     = xb;                          // alias (in-place gemm1)
    unsigned short* aggr1 = us;                          us += (size_t)N1_C * 256;
    unsigned short* aggr2 = aggr1;                       // alias (aggr1 dead after gemm1)
    unsigned short* wt1l  = us;                          us += 256 * 256;
    unsigned short* wt1r  = us;                          us += 256 * 256;
    unsigned short* wt2l  = us;                          us += 128 * 256;
    unsigned short* wt2r  = us;                          us += 128 * 256;
    int* ip = (int*)us;
    int* deg1      = ip;               ip += N1_C;       // deg1+deg2 adjacent (one zero)
    int* deg2      = ip;               ip += N2_C;
    int* rowstart1 = ip;               ip += N1_C;
    int* cursor1   = ip;               ip += N1_C;
    int* perm1     = ip;               ip += E1_C;
    int* rowstart2 = ip;               ip += N2_C;
    int* cursor2   = ip;               ip += N2_C;
    int* perm2     = ip;               ip += E2_C;

    // ---- precompute: x -> bf16, weights -> bf16 transposed ----
    convert_x_kernel<<<4096, 256, 0, stream>>>(x, xb, (N0_C * 256) / 4);
    transpose_all_w_kernel<<<768, 256, 0, stream>>>(W1l, W1r, W2l, W2r,
                                                    wt1l, wt1r, wt2l, wt2r);

    // ---- build CSR for both layers (fused launches) ----
    zero_int_kernel<<<64, 256, 0, stream>>>(deg1, N1_C + N2_C);
    hist_both_kernel<<<(E1_C + E2_C + 255) / 256, 256, 0, stream>>>(dst1, dst2,
                                                                    deg1, deg2);
    scan_both_kernel<<<2, 256, 0, stream>>>(deg1, rowstart1, cursor1,
                                            deg2, rowstart2, cursor2);
    permute_both_kernel<<<(E1_C + E2_C + 255) / 256, 256, 0, stream>>>(
        src1, dst1, cursor1, perm1, src2, dst2, cursor2, perm2);

    // ---- layer 1: gather-mean (bf16 xb -> bf16 aggr1), GEMM in place -> h ----
    gather_mean_bf16_kernel<<<(N1_C + 3) / 4, 256, 0, stream>>>(xb, rowstart1, cursor1,
                                                                perm1, aggr1,
                                                                N1_C, E1_C, N0_C);
    mfma_gemm1_kernel<<<(N1_C + 127) / 128, 512, 0, stream>>>(aggr1, xb, wt1l, wt1r,
                                                              b1, h, N1_C);

    // ---- layer 2: gather-mean (bf16 h -> bf16 aggr2), GEMM -> fp32 out ----
    gather_mean_bf16_kernel<<<(N2_C + 3) / 4, 256, 0, stream>>>(h, rowstart2, cursor2,
                                                                perm2, aggr2,
                                                                N2_C, E2_C, N1_C);
    {
        dim3 grid(D_OUT_C / 128, (N2_C + 127) / 128);   // (1, 79)
        mfma_gemm2_kernel<<<grid, 256, 0, stream>>>(aggr2, h, wt2l, wt2r, b2, out,
                                                    N2_C, D_OUT_C);
    }
}

// Round 9
// 394.404 us; speedup vs baseline: 8.5121x; 1.2021x over previous
//
#include <hip/hip_runtime.h>
#include <math.h>

// Problem constants (from reference)
#define N0_C  100000
#define N1_C  40000
#define N2_C  10000
#define E1_C  640000
#define E2_C  160000
#define D_IN_C  256
#define D_HID_C 256
#define D_OUT_C 128

// scan segmentation: layer1 blocks [0,157), layer2 blocks [157,197)
#define NB1_C 157
#define NB2_C 40
#define NBT_C 197

typedef __attribute__((ext_vector_type(8))) short short8;     // 8 bf16 (4 VGPRs)
typedef __attribute__((ext_vector_type(4))) float float4v;    // MFMA acc

// round-to-nearest-even fp32 -> bf16 bits
__device__ __forceinline__ unsigned short f2bf(float f) {
    unsigned int u = __float_as_uint(f);
    return (unsigned short)((u + 0x7FFFu + ((u >> 16) & 1u)) >> 16);
}
__device__ __forceinline__ float bf2f(unsigned int h) {
    return __uint_as_float(h << 16);
}

// ---------------------------------------------------------------------------
// zero fill for int arrays
// ---------------------------------------------------------------------------
__global__ void zero_int_kernel(int* __restrict__ p, int n) {
    int i = blockIdx.x * blockDim.x + threadIdx.x;
    int stride = gridDim.x * blockDim.x;
    for (; i < n; i += stride) p[i] = 0;
}

// ---------------------------------------------------------------------------
// fp32 -> bf16 bulk convert of x (float4 in, 4xbf16 packed u64 out)
// ---------------------------------------------------------------------------
__global__ void convert_x_kernel(const float* __restrict__ src,
                                 unsigned short* __restrict__ dst, int n4) {
    int i = blockIdx.x * blockDim.x + threadIdx.x;
    int stride = gridDim.x * blockDim.x;
    for (; i < n4; i += stride) {
        float4 v = ((const float4*)src)[i];
        unsigned long long u = (unsigned long long)f2bf(v.x)
                             | ((unsigned long long)f2bf(v.y) << 16)
                             | ((unsigned long long)f2bf(v.z) << 32)
                             | ((unsigned long long)f2bf(v.w) << 48);
        ((unsigned long long*)dst)[i] = u;
    }
}

// ---------------------------------------------------------------------------
// all 4 weight transposes in one launch: Wt[n][256+k] = bf16(W[k][n])
// ---------------------------------------------------------------------------
__global__ void transpose_all_w_kernel(const float* __restrict__ W1l,
                                       const float* __restrict__ W1r,
                                       const float* __restrict__ W2l,
                                       const float* __restrict__ W2r,
                                       unsigned short* __restrict__ wt1l,
                                       unsigned short* __restrict__ wt1r,
                                       unsigned short* __restrict__ wt2l,
                                       unsigned short* __restrict__ wt2r) {
    int id = blockIdx.x * blockDim.x + threadIdx.x;
    if (id >= 196608) return;
    const float* W; unsigned short* Wt; int N; int off;
    if (id < 65536)       { W = W1l; Wt = wt1l; N = 256; off = id; }
    else if (id < 131072) { W = W1r; Wt = wt1r; N = 256; off = id - 65536; }
    else if (id < 163840) { W = W2l; Wt = wt2l; N = 128; off = id - 131072; }
    else                  { W = W2r; Wt = wt2r; N = 128; off = id - 163840; }
    int k = off / N, n = off - k * N;        // consecutive off -> consecutive n (coalesced)
    Wt[n * 256 + k] = f2bf(W[off]);
}

// ---------------------------------------------------------------------------
// CSR build: fused histogram (indices clamped -> cannot fault)
// ---------------------------------------------------------------------------
__global__ void hist_both_kernel(const int* __restrict__ dst1,
                                 const int* __restrict__ dst2,
                                 int* __restrict__ deg1, int* __restrict__ deg2) {
    int e = blockIdx.x * blockDim.x + threadIdx.x;
    if (e < E1_C) {
        int d = min(max(dst1[e], 0), N1_C - 1);
        atomicAdd(&deg1[d], 1);
    } else if (e < E1_C + E2_C) {
        int d = min(max(dst2[e - E1_C], 0), N2_C - 1);
        atomicAdd(&deg2[d], 1);
    }
}

// ---------------------------------------------------------------------------
// 3-phase parallel segmented scan (layer1 = blocks [0,157), layer2 = rest)
// ---------------------------------------------------------------------------
__global__ __launch_bounds__(256)
void scan_phase_a_kernel(const int* __restrict__ deg1, const int* __restrict__ deg2,
                         int* __restrict__ pre, int* __restrict__ bsum) {
    const int b = blockIdx.x;
    const int tid = threadIdx.x;
    const int* deg; int i, n, gout;
    if (b < NB1_C) { deg = deg1; i = b * 256 + tid;            n = N1_C; gout = i; }
    else           { deg = deg2; i = (b - NB1_C) * 256 + tid;  n = N2_C; gout = N1_C + i; }
    int v = (i < n) ? deg[i] : 0;
    __shared__ int s[256];
    s[tid] = v;
    __syncthreads();
    for (int off = 1; off < 256; off <<= 1) {
        int t = (tid >= off) ? s[tid - off] : 0;
        __syncthreads();
        s[tid] += t;
        __syncthreads();
    }
    if (i < n) pre[gout] = s[tid] - v;       // exclusive within block
    if (tid == 255) bsum[b] = s[255];        // block total
}

__global__ __launch_bounds__(256)
void scan_phase_b_kernel(int* __restrict__ bsum) {   // in-place -> block offsets
    const int tid = threadIdx.x;
    __shared__ int s[256];
    // segment 1: blocks [0,157)
    int v1 = (tid < NB1_C) ? bsum[tid] : 0;
    s[tid] = v1;
    __syncthreads();
    for (int off = 1; off < 256; off <<= 1) {
        int t = (tid >= off) ? s[tid - off] : 0;
        __syncthreads();
        s[tid] += t;
        __syncthreads();
    }
    int e1 = s[tid] - v1;
    __syncthreads();
    // segment 2: blocks [157,197)
    int v2 = (tid < NB2_C) ? bsum[NB1_C + tid] : 0;
    s[tid] = v2;
    __syncthreads();
    for (int off = 1; off < 256; off <<= 1) {
        int t = (tid >= off) ? s[tid - off] : 0;
        __syncthreads();
        s[tid] += t;
        __syncthreads();
    }
    int e2 = s[tid] - v2;
    if (tid < NB1_C) bsum[tid] = e1;
    if (tid < NB2_C) bsum[NB1_C + tid] = e2;
}

__global__ __launch_bounds__(256)
void scan_phase_c_kernel(const int* __restrict__ pre, const int* __restrict__ bsum,
                         int* __restrict__ rs1, int* __restrict__ cur1,
                         int* __restrict__ rs2, int* __restrict__ cur2) {
    const int b = blockIdx.x;
    const int tid = threadIdx.x;
    const int off = bsum[b];
    if (b < NB1_C) {
        int i = b * 256 + tid;
        if (i < N1_C) { int v = pre[i] + off; rs1[i] = v; cur1[i] = v; }
    } else {
        int i = (b - NB1_C) * 256 + tid;
        if (i < N2_C) { int v = pre[N1_C + i] + off; rs2[i] = v; cur2[i] = v; }
    }
}

// ---------------------------------------------------------------------------
// fused permute (pos clamped)
// ---------------------------------------------------------------------------
__global__ void permute_both_kernel(const int* __restrict__ src1,
                                    const int* __restrict__ dst1,
                                    int* __restrict__ cur1, int* __restrict__ perm1,
                                    const int* __restrict__ src2,
                                    const int* __restrict__ dst2,
                                    int* __restrict__ cur2, int* __restrict__ perm2) {
    int e = blockIdx.x * blockDim.x + threadIdx.x;
    if (e < E1_C) {
        int d = min(max(dst1[e], 0), N1_C - 1);
        int pos = atomicAdd(&cur1[d], 1);
        pos = min(max(pos, 0), E1_C - 1);
        perm1[pos] = src1[e];
    } else if (e < E1_C + E2_C) {
        int e2 = e - E1_C;
        int d = min(max(dst2[e2], 0), N2_C - 1);
        int pos = atomicAdd(&cur2[d], 1);
        pos = min(max(pos, 0), E2_C - 1);
        perm2[pos] = src2[e2];
    }
}

// ---------------------------------------------------------------------------
// gather-mean, bf16 in -> bf16 out. One wave per node, lane = 4 channels (u64).
// ---------------------------------------------------------------------------
__global__ __launch_bounds__(256)
void gather_mean_bf16_kernel(const unsigned short* __restrict__ feat,
                             const int* __restrict__ rowstart,
                             const int* __restrict__ cursor,
                             const int* __restrict__ perm,
                             unsigned short* __restrict__ aggr,
                             int n, int E, int nfeat) {
    int node = blockIdx.x * 4 + (threadIdx.x >> 6);
    int lane = threadIdx.x & 63;
    if (node >= n) return;
    int beg = min(max(rowstart[node], 0), E);
    int end = min(max(cursor[node], beg), E);
    float a0 = 0.f, a1 = 0.f, a2 = 0.f, a3 = 0.f;
    int i = beg;
    for (; i + 4 <= end; i += 4) {
        int s0 = min(max(perm[i + 0], 0), nfeat - 1);
        int s1 = min(max(perm[i + 1], 0), nfeat - 1);
        int s2 = min(max(perm[i + 2], 0), nfeat - 1);
        int s3 = min(max(perm[i + 3], 0), nfeat - 1);
        unsigned long long u0 = *(const unsigned long long*)(feat + (size_t)s0 * 256 + lane * 4);
        unsigned long long u1 = *(const unsigned long long*)(feat + (size_t)s1 * 256 + lane * 4);
        unsigned long long u2 = *(const unsigned long long*)(feat + (size_t)s2 * 256 + lane * 4);
        unsigned long long u3 = *(const unsigned long long*)(feat + (size_t)s3 * 256 + lane * 4);
        a0 += bf2f((unsigned int)(u0      ) & 0xFFFFu) + bf2f((unsigned int)(u1      ) & 0xFFFFu)
            + bf2f((unsigned int)(u2      ) & 0xFFFFu) + bf2f((unsigned int)(u3      ) & 0xFFFFu);
        a1 += bf2f((unsigned int)(u0 >> 16) & 0xFFFFu) + bf2f((unsigned int)(u1 >> 16) & 0xFFFFu)
            + bf2f((unsigned int)(u2 >> 16) & 0xFFFFu) + bf2f((unsigned int)(u3 >> 16) & 0xFFFFu);
        a2 += bf2f((unsigned int)(u0 >> 32) & 0xFFFFu) + bf2f((unsigned int)(u1 >> 32) & 0xFFFFu)
            + bf2f((unsigned int)(u2 >> 32) & 0xFFFFu) + bf2f((unsigned int)(u3 >> 32) & 0xFFFFu);
        a3 += bf2f((unsigned int)(u0 >> 48)          ) + bf2f((unsigned int)(u1 >> 48)          )
            + bf2f((unsigned int)(u2 >> 48)          ) + bf2f((unsigned int)(u3 >> 48)          );
    }
    for (; i < end; ++i) {
        int s = min(max(perm[i], 0), nfeat - 1);
        unsigned long long u = *(const unsigned long long*)(feat + (size_t)s * 256 + lane * 4);
        a0 += bf2f((unsigned int)(u      ) & 0xFFFFu);
        a1 += bf2f((unsigned int)(u >> 16) & 0xFFFFu);
        a2 += bf2f((unsigned int)(u >> 32) & 0xFFFFu);
        a3 += bf2f((unsigned int)(u >> 48)          );
    }
    float inv = (end > beg) ? 1.0f / (float)(end - beg) : 0.0f;
    unsigned long long u = (unsigned long long)f2bf(a0 * inv)
                         | ((unsigned long long)f2bf(a1 * inv) << 16)
                         | ((unsigned long long)f2bf(a2 * inv) << 32)
                         | ((unsigned long long)f2bf(a3 * inv) << 48);
    *(unsigned long long*)(aggr + (size_t)node * 256 + lane * 4) = u;
}

// ---------------------------------------------------------------------------
// layer-1 MFMA GEMM, single column block: h = relu( A0@Wt0^T + A1@Wt1^T + b )
//   128 rows x 256 cols per block, 512 threads (8 waves, 2x4), grid (313).
//   out_bf ALIASES A1 (h overwrites xb in place): each block writes only the
//   rows it alone reads, and the epilogue strictly follows all K-loop reads.
// ---------------------------------------------------------------------------
__global__ __launch_bounds__(512)
void mfma_gemm1_kernel(const unsigned short* A0,
                       const unsigned short* A1,
                       const unsigned short* __restrict__ Wt0,
                       const unsigned short* __restrict__ Wt1,
                       const float* __restrict__ bias,
                       unsigned short* out_bf,
                       int M) {
    __shared__ unsigned short As[128][72];
    __shared__ unsigned short Bs[256][72];

    const int tid  = threadIdx.x;
    const int lane = tid & 63;
    const int wid  = tid >> 6;         // 0..7
    const int wm   = wid & 1;
    const int wn   = wid >> 1;
    const int lr   = lane & 15;
    const int kq   = lane >> 4;
    const int row0 = blockIdx.x * 128;

    float4v acc[4][4];
    #pragma unroll
    for (int a = 0; a < 4; ++a)
        #pragma unroll
        for (int b = 0; b < 4; ++b)
            #pragma unroll
            for (int c = 0; c < 4; ++c) acc[a][b][c] = 0.f;

    for (int p = 0; p < 2; ++p) {
        const unsigned short* A  = p ? A1  : A0;
        const unsigned short* __restrict__ Wt = p ? Wt1 : Wt0;
        for (int kt = 0; kt < 4; ++kt) {
            const int k0 = kt * 64;
            __syncthreads();
            #pragma unroll
            for (int i = 0; i < 2; ++i) {
                int idx = tid + i * 512;
                int r = idx >> 3, sc = (idx & 7) * 8;
                int row = row0 + r;
                if (row > M - 1) row = M - 1;
                *(short8*)&As[r][sc] = *(const short8*)(A + (size_t)row * 256 + k0 + sc);
            }
            #pragma unroll
            for (int i = 0; i < 4; ++i) {
                int idx = tid + i * 512;
                int r = idx >> 3, sc = (idx & 7) * 8;
                *(short8*)&Bs[r][sc] = *(const short8*)(Wt + (size_t)r * 256 + k0 + sc);
            }
            __syncthreads();
            #pragma unroll
            for (int ks = 0; ks < 64; ks += 32) {
                short8 af[4], bfr[4];
                #pragma unroll
                for (int t = 0; t < 4; ++t) {
                    af[t]  = *(const short8*)&As[wm * 64 + t * 16 + lr][ks + kq * 8];
                    bfr[t] = *(const short8*)&Bs[wn * 64 + t * 16 + lr][ks + kq * 8];
                }
                #pragma unroll
                for (int ar = 0; ar < 4; ++ar)
                    #pragma unroll
                    for (int bc = 0; bc < 4; ++bc)
                        acc[ar][bc] = __builtin_amdgcn_mfma_f32_16x16x32_bf16(
                            af[ar], bfr[bc], acc[ar][bc], 0, 0, 0);
            }
        }
    }

    #pragma unroll
    for (int bc = 0; bc < 4; ++bc) {
        int col = wn * 64 + bc * 16 + lr;
        float bv = bias[col];
        #pragma unroll
        for (int ar = 0; ar < 4; ++ar) {
            int rowb = row0 + wm * 64 + ar * 16 + kq * 4;
            #pragma unroll
            for (int i = 0; i < 4; ++i) {
                int row = rowb + i;
                if (row < M)
                    out_bf[(size_t)row * 256 + col] = f2bf(fmaxf(acc[ar][bc][i] + bv, 0.f));
            }
        }
    }
}

// ---------------------------------------------------------------------------
// layer-2 MFMA GEMM: out = sigmoid( A0@Wt0^T + A1@Wt1^T + b ), fp32 out
// ---------------------------------------------------------------------------
__global__ __launch_bounds__(256)
void mfma_gemm2_kernel(const unsigned short* __restrict__ A0,
                       const unsigned short* __restrict__ A1,
                       const unsigned short* __restrict__ Wt0,
                       const unsigned short* __restrict__ Wt1,
                       const float* __restrict__ bias,
                       float* __restrict__ out_f,
                       int M, int N) {
    __shared__ unsigned short As[128][72];
    __shared__ unsigned short Bs[128][72];

    const int tid  = threadIdx.x;
    const int lane = tid & 63;
    const int wid  = tid >> 6;
    const int wm   = wid & 1;
    const int wn   = wid >> 1;
    const int lr   = lane & 15;
    const int kq   = lane >> 4;
    const int row0 = blockIdx.y * 128;
    const int col0 = blockIdx.x * 128;

    const int sr = tid >> 3;
    const int sc = (tid & 7) * 8;

    float4v acc[4][4];
    #pragma unroll
    for (int a = 0; a < 4; ++a)
        #pragma unroll
        for (int b = 0; b < 4; ++b)
            #pragma unroll
            for (int c = 0; c < 4; ++c) acc[a][b][c] = 0.f;

    for (int p = 0; p < 2; ++p) {
        const unsigned short* __restrict__ A  = p ? A1  : A0;
        const unsigned short* __restrict__ Wt = p ? Wt1 : Wt0;
        for (int kt = 0; kt < 4; ++kt) {
            const int k0 = kt * 64;
            __syncthreads();
            #pragma unroll
            for (int rr = 0; rr < 128; rr += 32) {
                int row = row0 + sr + rr;
                if (row > M - 1) row = M - 1;
                *(short8*)&As[sr + rr][sc] =
                    *(const short8*)(A + (size_t)row * 256 + k0 + sc);
                int n = col0 + sr + rr;          // N multiple of 128
                *(short8*)&Bs[sr + rr][sc] =
                    *(const short8*)(Wt + (size_t)n * 256 + k0 + sc);
            }
            __syncthreads();
            #pragma unroll
            for (int ks = 0; ks < 64; ks += 32) {
                short8 af[4], bfr[4];
                #pragma unroll
                for (int t = 0; t < 4; ++t) {
                    af[t]  = *(const short8*)&As[wm * 64 + t * 16 + lr][ks + kq * 8];
                    bfr[t] = *(const short8*)&Bs[wn * 64 + t * 16 + lr][ks + kq * 8];
                }
                #pragma unroll
                for (int ar = 0; ar < 4; ++ar)
                    #pragma unroll
                    for (int bc = 0; bc < 4; ++bc)
                        acc[ar][bc] = __builtin_amdgcn_mfma_f32_16x16x32_bf16(
                            af[ar], bfr[bc], acc[ar][bc], 0, 0, 0);
            }
        }
    }

    #pragma unroll
    for (int bc = 0; bc < 4; ++bc) {
        int col = col0 + wn * 64 + bc * 16 + lr;
        float bv = bias[col];
        #pragma unroll
        for (int ar = 0; ar < 4; ++ar) {
            int rowb = row0 + wm * 64 + ar * 16 + kq * 4;
            #pragma unroll
            for (int i = 0; i < 4; ++i) {
                int row = rowb + i;
                if (row < M)
                    out_f[(size_t)row * N + col] =
                        1.0f / (1.0f + __expf(-(acc[ar][bc][i] + bv)));
            }
        }
    }
}

// ---------------------------------------------------------------------------
// launch
// ---------------------------------------------------------------------------
extern "C" void kernel_launch(void* const* d_in, const int* in_sizes, int n_in,
                              void* d_out, int out_size, void* d_ws, size_t ws_size,
                              hipStream_t stream) {
    const float* x   = (const float*)d_in[0];
    const float* W1l = (const float*)d_in[1];
    const float* b1  = (const float*)d_in[2];
    const float* W1r = (const float*)d_in[3];
    const float* W2l = (const float*)d_in[4];
    const float* b2  = (const float*)d_in[5];
    const float* W2r = (const float*)d_in[6];
    const int* src1  = (const int*)d_in[7];
    const int* dst1  = (const int*)d_in[8];
    const int* src2  = (const int*)d_in[9];
    const int* dst2  = (const int*)d_in[10];
    float* out = (float*)d_out;

    // workspace layout (~76.1 MB < R1-proven 92.4 MB budget)
    unsigned short* us = (unsigned short*)d_ws;
    unsigned short* xb    = us;                          us += (size_t)N0_C * 256;
    unsigned short* h     = xb;                          // alias (in-place gemm1)
    unsigned short* aggr1 = us;                          us += (size_t)N1_C * 256;
    unsigned short* aggr2 = aggr1;                       // alias (aggr1 dead after gemm1)
    unsigned short* wt1l  = us;                          us += 256 * 256;
    unsigned short* wt1r  = us;                          us += 256 * 256;
    unsigned short* wt2l  = us;                          us += 128 * 256;
    unsigned short* wt2r  = us;                          us += 128 * 256;
    int* ip = (int*)us;
    int* deg1      = ip;               ip += N1_C;       // deg1+deg2 adjacent (one zero)
    int* deg2      = ip;               ip += N2_C;
    int* rowstart1 = ip;               ip += N1_C;
    int* cursor1   = ip;               ip += N1_C;
    int* perm1     = ip;               ip += E1_C;
    int* rowstart2 = ip;               ip += N2_C;
    int* cursor2   = ip;               ip += N2_C;
    int* perm2     = ip;               ip += E2_C;
    int* pre       = ip;               ip += N1_C + N2_C;   // scan scratch
    int* bsum      = ip;               ip += 256;

    // ---- precompute: x -> bf16, weights -> bf16 transposed ----
    convert_x_kernel<<<4096, 256, 0, stream>>>(x, xb, (N0_C * 256) / 4);
    transpose_all_w_kernel<<<768, 256, 0, stream>>>(W1l, W1r, W2l, W2r,
                                                    wt1l, wt1r, wt2l, wt2r);

    // ---- build CSR for both layers ----
    zero_int_kernel<<<64, 256, 0, stream>>>(deg1, N1_C + N2_C);
    hist_both_kernel<<<(E1_C + E2_C + 255) / 256, 256, 0, stream>>>(dst1, dst2,
                                                                    deg1, deg2);
    scan_phase_a_kernel<<<NBT_C, 256, 0, stream>>>(deg1, deg2, pre, bsum);
    scan_phase_b_kernel<<<1, 256, 0, stream>>>(bsum);
    scan_phase_c_kernel<<<NBT_C, 256, 0, stream>>>(pre, bsum, rowstart1, cursor1,
                                                   rowstart2, cursor2);
    permute_both_kernel<<<(E1_C + E2_C + 255) / 256, 256, 0, stream>>>(
        src1, dst1, cursor1, perm1, src2, dst2, cursor2, perm2);

    // ---- layer 1: gather-mean (bf16 xb -> bf16 aggr1), GEMM in place -> h ----
    gather_mean_bf16_kernel<<<(N1_C + 3) / 4, 256, 0, stream>>>(xb, rowstart1, cursor1,
                                                                perm1, aggr1,
                                                                N1_C, E1_C, N0_C);
    mfma_gemm1_kernel<<<(N1_C + 127) / 128, 512, 0, stream>>>(aggr1, xb, wt1l, wt1r,
                                                              b1, h, N1_C);

    // ---- layer 2: gather-mean (bf16 h -> bf16 aggr2), GEMM -> fp32 out ----
    gather_mean_bf16_kernel<<<(N2_C + 3) / 4, 256, 0, stream>>>(h, rowstart2, cursor2,
                                                                perm2, aggr2,
                                                                N2_C, E2_C, N1_C);
    {
        dim3 grid(D_OUT_C / 128, (N2_C + 127) / 128);   // (1, 79)
        mfma_gemm2_kernel<<<grid, 256, 0, stream>>>(aggr2, h, wt2l, wt2r, b2, out,
                                                    N2_C, D_OUT_C);
    }
}